// Round 1
// baseline (323.260 us; speedup 1.0000x reference)
//
#include <hip/hip_runtime.h>
#include <cstdint>

// Problem constants
#define T_DIM 8192
#define D_DIM 1024
#define H_DIM 16
#define DH_DIM 64
#define NB_DIM 64

typedef __bf16 bf16x8 __attribute__((ext_vector_type(8)));
typedef __bf16 bf16x4 __attribute__((ext_vector_type(4)));
typedef float f32x4 __attribute__((ext_vector_type(4)));

#define MFMA16(a, b, c) __builtin_amdgcn_mfma_f32_16x16x32_bf16((a), (b), (c), 0, 0, 0)

// async global->LDS, 16B per lane. LDS dest must be wave-uniform base + lane*16.
__device__ __forceinline__ void gld_lds16(const void* gsrc, void* ldst) {
  __builtin_amdgcn_global_load_lds(
      (__attribute__((address_space(1))) void*)(uintptr_t)gsrc,
      (__attribute__((address_space(3))) void*)(uintptr_t)ldst,
      16, 0, 0);
}

// ---------------------------------------------------------------------------
// Weight convert + transpose: W[K][N] f32 -> Wt[N][K] bf16
// ---------------------------------------------------------------------------
__global__ __launch_bounds__(256) void transpose_cvt(
    const float* __restrict__ W, __bf16* __restrict__ Wt, int K, int N) {
  __shared__ float tile[32][33];
  const int tx = threadIdx.x & 31, ty = threadIdx.x >> 5;
  const int n0 = blockIdx.x * 32, k0 = blockIdx.y * 32;
#pragma unroll
  for (int i = 0; i < 32; i += 8)
    tile[ty + i][tx] = W[(size_t)(k0 + ty + i) * N + n0 + tx];
  __syncthreads();
#pragma unroll
  for (int i = 0; i < 32; i += 8)
    Wt[(size_t)(n0 + ty + i) * K + k0 + tx] = (__bf16)tile[tx][ty + i];
}

// ---------------------------------------------------------------------------
// LayerNorm: x[row][1024] f32 -> out bf16. One block (256 thr) per row.
// ---------------------------------------------------------------------------
__global__ __launch_bounds__(256) void ln_kernel(
    const float* __restrict__ x, const float* __restrict__ g,
    const float* __restrict__ b, __bf16* __restrict__ out) {
  __shared__ float red[8];
  const int row = blockIdx.x, tid = threadIdx.x;
  const float4 v = ((const float4*)(x + (size_t)row * D_DIM))[tid];
  float s = v.x + v.y + v.z + v.w;
#pragma unroll
  for (int off = 32; off >= 1; off >>= 1) s += __shfl_xor(s, off, 64);
  if ((tid & 63) == 0) red[tid >> 6] = s;
  __syncthreads();
  const float mean = (red[0] + red[1] + red[2] + red[3]) * (1.0f / D_DIM);
  const float d0 = v.x - mean, d1 = v.y - mean, d2 = v.z - mean, d3 = v.w - mean;
  float ss = d0 * d0 + d1 * d1 + d2 * d2 + d3 * d3;
#pragma unroll
  for (int off = 32; off >= 1; off >>= 1) ss += __shfl_xor(ss, off, 64);
  if ((tid & 63) == 0) red[4 + (tid >> 6)] = ss;
  __syncthreads();
  const float var = (red[4] + red[5] + red[6] + red[7]) * (1.0f / D_DIM);
  const float rstd = rsqrtf(var + 1e-5f);
  const float4 gg = ((const float4*)g)[tid];
  const float4 bb = ((const float4*)b)[tid];
  bf16x4 o;
  o[0] = (__bf16)(d0 * rstd * gg.x + bb.x);
  o[1] = (__bf16)(d1 * rstd * gg.y + bb.y);
  o[2] = (__bf16)(d2 * rstd * gg.z + bb.z);
  o[3] = (__bf16)(d3 * rstd * gg.w + bb.w);
  *(bf16x4*)(out + (size_t)row * D_DIM + tid * 4) = o;
}

// ---------------------------------------------------------------------------
// GEMM C[M][N] = A[M][K] (bf16) * Bt[N][K]^T (bf16), m97 structure:
// 128x128 tile, BK=64, 4 waves (each 64x64 = 4x4 16x16 frags),
// global_load_lds width-16 staging, double-buffered LDS, 2-phase loop.
// EPI: 0 = bf16 store; 1 = bf16 transposed store (Ct[col*M+row]);
//      2 = f32 store with residual add; 3 = silu -> bf16 store.
// ---------------------------------------------------------------------------
template <int EPI>
__global__ __launch_bounds__(256, 2) void gemm_bt(
    const __bf16* __restrict__ A, const __bf16* __restrict__ Bt,
    const float* __restrict__ Res, void* __restrict__ Cout,
    int M, int N, int K) {
  __shared__ __bf16 As[2][128 * 64];
  __shared__ __bf16 Bs[2][128 * 64];
  const int tid = threadIdx.x;
  const int l = tid & 63, w = tid >> 6;
  const int lr = l & 15, lg = l >> 4;
  const int wr = w >> 1, wc = w & 1;
  const int bm = blockIdx.y, bn = blockIdx.x;
  const size_t arow0 = (size_t)bm * 128;
  const size_t brow0 = (size_t)bn * 128;

  f32x4 acc[4][4];
  const f32x4 z4 = {0.f, 0.f, 0.f, 0.f};
#pragma unroll
  for (int m = 0; m < 4; ++m)
#pragma unroll
    for (int n = 0; n < 4; ++n) acc[m][n] = z4;

  auto stage = [&](int buf, int k0) {
#pragma unroll
    for (int r = 0; r < 4; ++r) {
      int ci = r * 256 + tid;
      int row = ci >> 3, c8 = ci & 7;
      gld_lds16(A + (arow0 + row) * K + k0 + c8 * 8, &As[buf][ci * 8]);
    }
#pragma unroll
    for (int r = 0; r < 4; ++r) {
      int ci = r * 256 + tid;
      int row = ci >> 3, c8 = ci & 7;
      gld_lds16(Bt + (brow0 + row) * K + k0 + c8 * 8, &Bs[buf][ci * 8]);
    }
  };

  stage(0, 0);
  const int nk = K >> 6;
  int cur = 0;
  __syncthreads();  // drains vmcnt(0) before first reads

  for (int t = 0; t < nk; ++t) {
    if (t + 1 < nk) stage(cur ^ 1, (t + 1) << 6);
#pragma unroll
    for (int kk = 0; kk < 2; ++kk) {
      bf16x8 af[4], bf_[4];
#pragma unroll
      for (int m = 0; m < 4; ++m)
        af[m] = *(const bf16x8*)&As[cur][(wr * 64 + m * 16 + lr) * 64 + kk * 32 + lg * 8];
#pragma unroll
      for (int n = 0; n < 4; ++n)
        bf_[n] = *(const bf16x8*)&Bs[cur][(wc * 64 + n * 16 + lr) * 64 + kk * 32 + lg * 8];
#pragma unroll
      for (int m = 0; m < 4; ++m)
#pragma unroll
        for (int n = 0; n < 4; ++n) acc[m][n] = MFMA16(af[m], bf_[n], acc[m][n]);
    }
    __syncthreads();  // stage complete + all reads of As[cur] done
    cur ^= 1;
  }

  // Epilogue. C/D frag layout (m89): col = lane&15, row = (lane>>4)*4 + reg.
  const int row0 = bm * 128 + wr * 64;
  const int col0 = bn * 128 + wc * 64;
#pragma unroll
  for (int m = 0; m < 4; ++m)
#pragma unroll
    for (int n = 0; n < 4; ++n)
#pragma unroll
      for (int r = 0; r < 4; ++r) {
        const int row = row0 + m * 16 + lg * 4 + r;
        const int col = col0 + n * 16 + lr;
        const float v = acc[m][n][r];
        if constexpr (EPI == 0) {
          ((__bf16*)Cout)[(size_t)row * N + col] = (__bf16)v;
        } else if constexpr (EPI == 1) {
          ((__bf16*)Cout)[(size_t)col * M + row] = (__bf16)v;
        } else if constexpr (EPI == 2) {
          const size_t idx = (size_t)row * N + col;
          ((float*)Cout)[idx] = v + Res[idx];
        } else {
          const float sv = v / (1.f + __expf(-v));
          ((__bf16*)Cout)[(size_t)row * N + col] = (__bf16)sv;
        }
      }
}

// ---------------------------------------------------------------------------
// Block-local attention. One block per (head, qblock). 4 waves x 32 q-rows.
// q,k: [T][D] bf16 (head cols). vT: [D][T] bf16. out: [T][D] bf16.
// K and V^T staged via global_load_lds with XOR chunk swizzle
// (linear LDS dest + inverse-swizzled global source + swizzled read).
// ---------------------------------------------------------------------------
__global__ __launch_bounds__(256, 2) void attn_kernel(
    const __bf16* __restrict__ q, const __bf16* __restrict__ k,
    const __bf16* __restrict__ vT, __bf16* __restrict__ out) {
  // Kt: element (kv,d) at chunk kv*8 + ((d>>3) ^ (kv&7)), elem = chunk*8 + (d&7)
  __shared__ __bf16 Kt[128 * 64];
  // Vt: element (d,kv) at chunk d*16 + ((kv>>3) ^ (d&7)), elem = chunk*8 + (kv&7)
  __shared__ __bf16 Vt[64 * 128];
  __shared__ __bf16 Pl[4][32 * 136];  // per-wave P, padded rows (136*2B, 16B-mult)

  const int tid = threadIdx.x;
  const int l = tid & 63, w = tid >> 6;
  const int lr = l & 15, lg = l >> 4;
  const int h = blockIdx.x >> 6;
  const int blk = blockIdx.x & 63;

  // Q fragments in registers: rows w*32 + m*16 + lr, d = ks*32 + lg*8
  bf16x8 qf[2][2];
#pragma unroll
  for (int m = 0; m < 2; ++m)
#pragma unroll
    for (int ks = 0; ks < 2; ++ks)
      qf[m][ks] = *(const bf16x8*)(q + (size_t)(blk * 128 + w * 32 + m * 16 + lr) * D_DIM +
                                   h * 64 + ks * 32 + lg * 8);

  const f32x4 z4 = {0.f, 0.f, 0.f, 0.f};
  float mrun[2][4], srun[2][4];
  f32x4 o[2][4];
#pragma unroll
  for (int m = 0; m < 2; ++m) {
#pragma unroll
    for (int r = 0; r < 4; ++r) { mrun[m][r] = -3.0e38f; srun[m][r] = 0.f; }
#pragma unroll
    for (int n = 0; n < 4; ++n) o[m][n] = z4;
  }

  for (int kb = blk - 1; kb <= blk + 1; ++kb) {
    if (kb < 0 || kb >= NB_DIM) continue;  // uniform per block
    // ---- stage K block (linear dest, source col-chunk XOR kv&7) ----
#pragma unroll
    for (int r = 0; r < 4; ++r) {
      int ci = r * 256 + tid;
      int kv = ci >> 3, c = ci & 7;
      gld_lds16(k + (size_t)(kb * 128 + kv) * D_DIM + h * 64 + ((c ^ (kv & 7)) << 3),
                &Kt[ci * 8]);
    }
    // ---- stage V^T block (source kv-chunk XOR d&7) ----
#pragma unroll
    for (int r = 0; r < 4; ++r) {
      int ci = r * 256 + tid;
      int d = ci >> 4, c = ci & 15;
      gld_lds16(vT + (size_t)(h * 64 + d) * T_DIM + kb * 128 + ((c ^ (d & 7)) << 3),
                &Vt[ci * 8]);
    }
    __syncthreads();

    // ---- S = Q K^T ----
    f32x4 s[2][8];
#pragma unroll
    for (int m = 0; m < 2; ++m)
#pragma unroll
      for (int kc = 0; kc < 8; ++kc) s[m][kc] = z4;
#pragma unroll
    for (int ks = 0; ks < 2; ++ks) {
#pragma unroll
      for (int kc = 0; kc < 8; ++kc) {
        const int kvr = kc * 16 + lr;
        const int cc = (ks * 4 + lg) ^ (kvr & 7);
        const bf16x8 bfrag = *(const bf16x8*)&Kt[(kvr * 8 + cc) * 8];
        s[0][kc] = MFMA16(qf[0][ks], bfrag, s[0][kc]);
        s[1][kc] = MFMA16(qf[1][ks], bfrag, s[1][kc]);
      }
    }

    // ---- scale + band mask + online softmax ----
    const int rel = kb - blk;
#pragma unroll
    for (int m = 0; m < 2; ++m) {
#pragma unroll
      for (int r = 0; r < 4; ++r) {
        const int qi = w * 32 + m * 16 + lg * 4 + r;
        float rm = -3.0e38f;
#pragma unroll
        for (int kc = 0; kc < 8; ++kc) {
          const int kj = kc * 16 + lr;
          float v = s[m][kc][r] * 0.125f;
          const bool valid = (rel == 0) || (rel < 0 ? (kj >= qi) : (kj <= qi));
          v = valid ? v : -3.0e38f;
          s[m][kc][r] = v;
          rm = fmaxf(rm, v);
        }
#pragma unroll
        for (int off = 1; off < 16; off <<= 1) rm = fmaxf(rm, __shfl_xor(rm, off, 64));
        const float mnew = fmaxf(mrun[m][r], rm);
        const float scale = __expf(mrun[m][r] - mnew);
        float rs = 0.f;
#pragma unroll
        for (int kc = 0; kc < 8; ++kc) {
          const float p = __expf(s[m][kc][r] - mnew);
          s[m][kc][r] = p;
          rs += p;
        }
#pragma unroll
        for (int off = 1; off < 16; off <<= 1) rs += __shfl_xor(rs, off, 64);
        srun[m][r] = srun[m][r] * scale + rs;
        mrun[m][r] = mnew;
#pragma unroll
        for (int n = 0; n < 4; ++n) o[m][n][r] *= scale;
      }
    }

    // ---- P -> LDS (per-wave region) ----
    __bf16* Pw = Pl[w];
#pragma unroll
    for (int m = 0; m < 2; ++m)
#pragma unroll
      for (int kc = 0; kc < 8; ++kc)
#pragma unroll
        for (int r = 0; r < 4; ++r)
          Pw[(m * 16 + lg * 4 + r) * 136 + kc * 16 + lr] = (__bf16)s[m][kc][r];
    __syncthreads();  // P visible (and Kt reads done)

    // ---- O += P V ----
#pragma unroll
    for (int ks = 0; ks < 4; ++ks) {
      bf16x8 pa[2];
#pragma unroll
      for (int m = 0; m < 2; ++m)
        pa[m] = *(const bf16x8*)&Pw[(m * 16 + lr) * 136 + ks * 32 + lg * 8];
#pragma unroll
      for (int n = 0; n < 4; ++n) {
        const int d = n * 16 + lr;
        const int cc = (ks * 4 + lg) ^ (d & 7);
        const bf16x8 vb = *(const bf16x8*)&Vt[(d * 16 + cc) * 8];
        o[0][n] = MFMA16(pa[0], vb, o[0][n]);
        o[1][n] = MFMA16(pa[1], vb, o[1][n]);
      }
    }
    __syncthreads();  // Vt/Pl safe to overwrite next iteration
  }

  // ---- finalize: O / rowsum -> out[T][D] ----
#pragma unroll
  for (int m = 0; m < 2; ++m)
#pragma unroll
    for (int n = 0; n < 4; ++n)
#pragma unroll
      for (int r = 0; r < 4; ++r) {
        const float val = o[m][n][r] / srun[m][r];
        out[(size_t)(blk * 128 + w * 32 + m * 16 + lg * 4 + r) * D_DIM +
            h * 64 + n * 16 + lr] = (__bf16)val;
      }
}

// ---------------------------------------------------------------------------
extern "C" void kernel_launch(void* const* d_in, const int* in_sizes, int n_in,
                              void* d_out, int out_size, void* d_ws, size_t ws_size,
                              hipStream_t stream) {
  (void)in_sizes; (void)n_in; (void)out_size; (void)ws_size;
  const float* x      = (const float*)d_in[0];
  const float* wq     = (const float*)d_in[1];
  const float* wk     = (const float*)d_in[2];
  const float* wv     = (const float*)d_in[3];
  const float* wo     = (const float*)d_in[4];
  const float* wg     = (const float*)d_in[5];
  const float* wd     = (const float*)d_in[6];
  const float* norm_g = (const float*)d_in[7];
  const float* norm_b = (const float*)d_in[8];
  const float* ffn_g  = (const float*)d_in[9];
  const float* ffn_b  = (const float*)d_in[10];
  float* out = (float*)d_out;

  // Workspace layout (112 MB total)
  char* ws = (char*)d_ws;
  constexpr size_t MB = 1ull << 20;
  __bf16* wqT  = (__bf16*)(ws + 0 * MB);    // [1024][1024]
  __bf16* wkT  = (__bf16*)(ws + 2 * MB);
  __bf16* wvT  = (__bf16*)(ws + 4 * MB);
  __bf16* woT  = (__bf16*)(ws + 6 * MB);
  __bf16* wgT  = (__bf16*)(ws + 8 * MB);    // [2048][1024]
  __bf16* wdT  = (__bf16*)(ws + 12 * MB);   // [1024][2048]
  __bf16* hbuf = (__bf16*)(ws + 16 * MB);   // h / attn_out / h2 (16 MB, reused)
  __bf16* qbf  = (__bf16*)(ws + 32 * MB);   // [T][D]
  __bf16* kbf  = (__bf16*)(ws + 48 * MB);   // [T][D]
  __bf16* vTbf = (__bf16*)(ws + 64 * MB);   // [D][T]
  float*  x2   = (float*)(ws + 80 * MB);    // [T][D] f32 (32 MB)
  __bf16* gbf  = (__bf16*)(ws + 32 * MB);   // [T][2D], reuses q+k (dead by then)

  // 1. weight transpose+convert
  transpose_cvt<<<dim3(32, 32), 256, 0, stream>>>(wq, wqT, 1024, 1024);
  transpose_cvt<<<dim3(32, 32), 256, 0, stream>>>(wk, wkT, 1024, 1024);
  transpose_cvt<<<dim3(32, 32), 256, 0, stream>>>(wv, wvT, 1024, 1024);
  transpose_cvt<<<dim3(32, 32), 256, 0, stream>>>(wo, woT, 1024, 1024);
  transpose_cvt<<<dim3(64, 32), 256, 0, stream>>>(wg, wgT, 1024, 2048);
  transpose_cvt<<<dim3(32, 64), 256, 0, stream>>>(wd, wdT, 2048, 1024);

  // 2. LN1
  ln_kernel<<<8192, 256, 0, stream>>>(x, norm_g, norm_b, hbuf);

  // 3. QKV projections (v written transposed for attention staging)
  gemm_bt<0><<<dim3(8, 64), 256, 0, stream>>>(hbuf, wqT, nullptr, qbf, 8192, 1024, 1024);
  gemm_bt<0><<<dim3(8, 64), 256, 0, stream>>>(hbuf, wkT, nullptr, kbf, 8192, 1024, 1024);
  gemm_bt<1><<<dim3(8, 64), 256, 0, stream>>>(hbuf, wvT, nullptr, vTbf, 8192, 1024, 1024);

  // 4. local attention -> hbuf (h dead)
  attn_kernel<<<1024, 256, 0, stream>>>(qbf, kbf, vTbf, hbuf);

  // 5. out-proj + residual: x2 = x + attn @ wo
  gemm_bt<2><<<dim3(8, 64), 256, 0, stream>>>(hbuf, woT, x, x2, 8192, 1024, 1024);

  // 6. LN2 -> hbuf (attn dead)
  ln_kernel<<<8192, 256, 0, stream>>>(x2, ffn_g, ffn_b, hbuf);

  // 7. gate: g = silu(h2 @ wg)
  gemm_bt<3><<<dim3(16, 64), 256, 0, stream>>>(hbuf, wgT, nullptr, gbf, 8192, 2048, 1024);

  // 8. down + residual: out = x2 + g @ wd
  gemm_bt<2><<<dim3(8, 64), 256, 0, stream>>>(gbf, wdT, x2, out, 8192, 1024, 2048);
}

// Round 2
// 307.813 us; speedup vs baseline: 1.0502x; 1.0502x over previous
//
#include <hip/hip_runtime.h>
#include <cstdint>

// Problem constants
#define T_DIM 8192
#define D_DIM 1024
#define H_DIM 16
#define DH_DIM 64
#define NB_DIM 64

typedef __bf16 bf16x8 __attribute__((ext_vector_type(8)));
typedef __bf16 bf16x4 __attribute__((ext_vector_type(4)));
typedef float f32x4 __attribute__((ext_vector_type(4)));

#define MFMA16(a, b, c) __builtin_amdgcn_mfma_f32_16x16x32_bf16((a), (b), (c), 0, 0, 0)

// async global->LDS, 16B per lane. LDS dest must be wave-uniform base + lane*16.
__device__ __forceinline__ void gld_lds16(const void* gsrc, void* ldst) {
  __builtin_amdgcn_global_load_lds(
      (__attribute__((address_space(1))) void*)(uintptr_t)gsrc,
      (__attribute__((address_space(3))) void*)(uintptr_t)ldst,
      16, 0, 0);
}

// ---------------------------------------------------------------------------
// Weight convert + transpose: W[K][N] f32 -> Wt[N][K] bf16
// ---------------------------------------------------------------------------
__global__ __launch_bounds__(256) void transpose_cvt(
    const float* __restrict__ W, __bf16* __restrict__ Wt, int K, int N) {
  __shared__ float tile[32][33];
  const int tx = threadIdx.x & 31, ty = threadIdx.x >> 5;
  const int n0 = blockIdx.x * 32, k0 = blockIdx.y * 32;
#pragma unroll
  for (int i = 0; i < 32; i += 8)
    tile[ty + i][tx] = W[(size_t)(k0 + ty + i) * N + n0 + tx];
  __syncthreads();
#pragma unroll
  for (int i = 0; i < 32; i += 8)
    Wt[(size_t)(n0 + ty + i) * K + k0 + tx] = (__bf16)tile[tx][ty + i];
}

// ---------------------------------------------------------------------------
// LayerNorm: x[row][1024] f32 -> out bf16. One block (256 thr) per row.
// ---------------------------------------------------------------------------
__global__ __launch_bounds__(256) void ln_kernel(
    const float* __restrict__ x, const float* __restrict__ g,
    const float* __restrict__ b, __bf16* __restrict__ out) {
  __shared__ float red[8];
  const int row = blockIdx.x, tid = threadIdx.x;
  const float4 v = ((const float4*)(x + (size_t)row * D_DIM))[tid];
  float s = v.x + v.y + v.z + v.w;
#pragma unroll
  for (int off = 32; off >= 1; off >>= 1) s += __shfl_xor(s, off, 64);
  if ((tid & 63) == 0) red[tid >> 6] = s;
  __syncthreads();
  const float mean = (red[0] + red[1] + red[2] + red[3]) * (1.0f / D_DIM);
  const float d0 = v.x - mean, d1 = v.y - mean, d2 = v.z - mean, d3 = v.w - mean;
  float ss = d0 * d0 + d1 * d1 + d2 * d2 + d3 * d3;
#pragma unroll
  for (int off = 32; off >= 1; off >>= 1) ss += __shfl_xor(ss, off, 64);
  if ((tid & 63) == 0) red[4 + (tid >> 6)] = ss;
  __syncthreads();
  const float var = (red[4] + red[5] + red[6] + red[7]) * (1.0f / D_DIM);
  const float rstd = rsqrtf(var + 1e-5f);
  const float4 gg = ((const float4*)g)[tid];
  const float4 bb = ((const float4*)b)[tid];
  bf16x4 o;
  o[0] = (__bf16)(d0 * rstd * gg.x + bb.x);
  o[1] = (__bf16)(d1 * rstd * gg.y + bb.y);
  o[2] = (__bf16)(d2 * rstd * gg.z + bb.z);
  o[3] = (__bf16)(d3 * rstd * gg.w + bb.w);
  *(bf16x4*)(out + (size_t)row * D_DIM + tid * 4) = o;
}

// ---------------------------------------------------------------------------
// GEMM C[M][N] = A[M][K] (bf16) * Bt[N][K]^T (bf16), m97 structure:
// 128x128 tile, BK=64, 4 waves (each 64x64 = 4x4 16x16 frags),
// global_load_lds width-16 staging, double-buffered LDS, 2-phase loop.
// EPI: 0 = bf16 store; 1 = bf16 transposed store via LDS transpose;
//      2 = f32 store with residual add; 3 = silu -> bf16 store.
// ---------------------------------------------------------------------------
template <int EPI>
__global__ __launch_bounds__(256, 2) void gemm_bt(
    const __bf16* __restrict__ A, const __bf16* __restrict__ Bt,
    const float* __restrict__ Res, void* __restrict__ Cout,
    int M, int N, int K) {
  __shared__ __bf16 smem[32768];  // 64 KB: As[2][8192] | Bs[2][8192]
  __bf16* As = smem;
  __bf16* Bs = smem + 16384;
  const int tid = threadIdx.x;
  const int l = tid & 63, w = tid >> 6;
  const int lr = l & 15, lg = l >> 4;
  const int wr = w >> 1, wc = w & 1;
  const int bm = blockIdx.y, bn = blockIdx.x;
  const size_t arow0 = (size_t)bm * 128;
  const size_t brow0 = (size_t)bn * 128;

  f32x4 acc[4][4];
  const f32x4 z4 = {0.f, 0.f, 0.f, 0.f};
#pragma unroll
  for (int m = 0; m < 4; ++m)
#pragma unroll
    for (int n = 0; n < 4; ++n) acc[m][n] = z4;

  auto stage = [&](int buf, int k0) {
#pragma unroll
    for (int r = 0; r < 4; ++r) {
      int ci = r * 256 + tid;
      int row = ci >> 3, c8 = ci & 7;
      gld_lds16(A + (arow0 + row) * K + k0 + c8 * 8, &As[buf * 8192 + ci * 8]);
    }
#pragma unroll
    for (int r = 0; r < 4; ++r) {
      int ci = r * 256 + tid;
      int row = ci >> 3, c8 = ci & 7;
      gld_lds16(Bt + (brow0 + row) * K + k0 + c8 * 8, &Bs[buf * 8192 + ci * 8]);
    }
  };

  stage(0, 0);
  const int nk = K >> 6;
  int cur = 0;
  __syncthreads();  // drains vmcnt(0) before first reads

  for (int t = 0; t < nk; ++t) {
    if (t + 1 < nk) stage(cur ^ 1, (t + 1) << 6);
#pragma unroll
    for (int kk = 0; kk < 2; ++kk) {
      bf16x8 af[4], bf_[4];
#pragma unroll
      for (int m = 0; m < 4; ++m)
        af[m] = *(const bf16x8*)&As[cur * 8192 + (wr * 64 + m * 16 + lr) * 64 + kk * 32 + lg * 8];
#pragma unroll
      for (int n = 0; n < 4; ++n)
        bf_[n] = *(const bf16x8*)&Bs[cur * 8192 + (wc * 64 + n * 16 + lr) * 64 + kk * 32 + lg * 8];
#pragma unroll
      for (int m = 0; m < 4; ++m)
#pragma unroll
        for (int n = 0; n < 4; ++n) acc[m][n] = MFMA16(af[m], bf_[n], acc[m][n]);
    }
    __syncthreads();  // stage complete + all reads of As[cur] done
    cur ^= 1;
  }

  // Epilogue. C/D frag layout (m89): col = lane&15, row = (lane>>4)*4 + reg.
  const int row0 = bm * 128 + wr * 64;
  const int col0 = bn * 128 + wc * 64;
  if constexpr (EPI == 1) {
    // Transposed bf16 store via LDS: Tt[c(128)][136] over the smem region.
    // After the K-loop's final __syncthreads all LDS reads are drained.
    __bf16* Tt = smem;  // 128*136*2 = 34816 B <= 64 KB
#pragma unroll
    for (int m = 0; m < 4; ++m)
#pragma unroll
      for (int n = 0; n < 4; ++n)
#pragma unroll
        for (int r = 0; r < 4; ++r)
          Tt[(wc * 64 + n * 16 + lr) * 136 + wr * 64 + m * 16 + lg * 4 + r] =
              (__bf16)acc[m][n][r];
    __syncthreads();
#pragma unroll
    for (int i = 0; i < 8; ++i) {
      const int ci = i * 256 + tid;
      const int c = ci >> 4;           // local col 0..127
      const int rr = (ci & 15) * 8;    // local row 0..120
      const bf16x8 vv = *(const bf16x8*)&Tt[c * 136 + rr];
      *(bf16x8*)((__bf16*)Cout + (size_t)(bn * 128 + c) * M + bm * 128 + rr) = vv;
    }
    return;
  }
#pragma unroll
  for (int m = 0; m < 4; ++m)
#pragma unroll
    for (int n = 0; n < 4; ++n)
#pragma unroll
      for (int r = 0; r < 4; ++r) {
        const int row = row0 + m * 16 + lg * 4 + r;
        const int col = col0 + n * 16 + lr;
        const float v = acc[m][n][r];
        if constexpr (EPI == 0) {
          ((__bf16*)Cout)[(size_t)row * N + col] = (__bf16)v;
        } else if constexpr (EPI == 2) {
          const size_t idx = (size_t)row * N + col;
          ((float*)Cout)[idx] = v + Res[idx];
        } else {
          const float sv = v / (1.f + __expf(-v));
          ((__bf16*)Cout)[(size_t)row * N + col] = (__bf16)sv;
        }
      }
}

// ---------------------------------------------------------------------------
// Block-local attention v2 — BARRIER-FREE.
// One block per (head, qblock), 4 waves x 32 q-rows. K and V^T fragments are
// loaded DIRECTLY global->VGPR (every 16B lane load fully consumed; L1/L2
// serve the 3x neighbor-block reuse). Only per-wave P (and the output tile)
// round-trips through LDS — within-wave ordering, zero __syncthreads.
// Fully-masked 32-kv tiles of the prev/next blocks are skipped (wave-uniform).
// ---------------------------------------------------------------------------
__global__ __launch_bounds__(256, 2) void attn_kernel(
    const __bf16* __restrict__ q, const __bf16* __restrict__ k,
    const __bf16* __restrict__ vT, __bf16* __restrict__ out) {
  __shared__ __bf16 Pl[4][32 * 136];  // per-wave P / out staging (34 KB)

  const int tid = threadIdx.x;
  const int l = tid & 63, w = tid >> 6;
  const int lr = l & 15, lg = l >> 4;
  // XCD-chunked swizzle: 1024 blocks -> each XCD gets a contiguous 128-chunk
  const int bx = (int)blockIdx.x;
  const int swz = (bx & 7) * 128 + (bx >> 3);
  const int h = swz >> 6;
  const int blk = swz & 63;
  __bf16* Pw = Pl[w];

  // Q fragments in registers: rows w*32 + m*16 + lr, d = ks*32 + lg*8
  const __bf16* qbase =
      q + (size_t)(blk * 128 + w * 32 + lr) * D_DIM + h * 64 + lg * 8;
  bf16x8 qf[2][2];
#pragma unroll
  for (int m = 0; m < 2; ++m)
#pragma unroll
    for (int ks = 0; ks < 2; ++ks)
      qf[m][ks] = *(const bf16x8*)(qbase + m * 16 * D_DIM + ks * 32);

  const f32x4 z4 = {0.f, 0.f, 0.f, 0.f};
  float mrun[2][4], srun[2][4];
  f32x4 o[2][4];
#pragma unroll
  for (int m = 0; m < 2; ++m) {
#pragma unroll
    for (int r = 0; r < 4; ++r) { mrun[m][r] = -3.0e38f; srun[m][r] = 0.f; }
#pragma unroll
    for (int n = 0; n < 4; ++n) o[m][n] = z4;
  }

  for (int it = 0; it < 3; ++it) {
    const int kb = blk + it - 1;
    if (kb < 0 || kb >= NB_DIM) continue;  // uniform per block
    const int rel = it - 1;
    // tile-skip bounds (16-kv tiles, at 32-kv granularity shared by both m):
    // rel<0: valid kj>=qi -> keep kc >= 2w ; rel>0: valid kj<=qi -> keep kc < 2w+2
    const int kclo = (rel < 0) ? (w * 2) : 0;
    const int kchi = (rel > 0) ? (w * 2 + 2) : 8;

    // ---- S = Q K^T (direct K frags from global) ----
    f32x4 s[2][8];
    const __bf16* kbase =
        k + (size_t)(kb * 128 + lr) * D_DIM + h * 64 + lg * 8;
#pragma unroll
    for (int kc = 0; kc < 8; ++kc) {
      if (kc < kclo || kc >= kchi) continue;
      const bf16x8 k0 = *(const bf16x8*)(kbase + (size_t)kc * 16 * D_DIM);
      const bf16x8 k1 = *(const bf16x8*)(kbase + (size_t)kc * 16 * D_DIM + 32);
      s[0][kc] = MFMA16(qf[0][0], k0, z4);
      s[1][kc] = MFMA16(qf[1][0], k0, z4);
      s[0][kc] = MFMA16(qf[0][1], k1, s[0][kc]);
      s[1][kc] = MFMA16(qf[1][1], k1, s[1][kc]);
    }

    // ---- scale + band mask + online softmax ----
#pragma unroll
    for (int m = 0; m < 2; ++m) {
#pragma unroll
      for (int r = 0; r < 4; ++r) {
        const int qi = w * 32 + m * 16 + lg * 4 + r;
        float rm = -3.0e38f;
#pragma unroll
        for (int kc = 0; kc < 8; ++kc) {
          if (kc < kclo || kc >= kchi) continue;
          const int kj = kc * 16 + lr;
          float v = s[m][kc][r] * 0.125f;
          const bool valid = (rel == 0) || (rel < 0 ? (kj >= qi) : (kj <= qi));
          v = valid ? v : -3.0e38f;
          s[m][kc][r] = v;
          rm = fmaxf(rm, v);
        }
#pragma unroll
        for (int off = 1; off < 16; off <<= 1) rm = fmaxf(rm, __shfl_xor(rm, off, 64));
        const float mnew = fmaxf(mrun[m][r], rm);
        const float scale = __expf(mrun[m][r] - mnew);
        float rs = 0.f;
#pragma unroll
        for (int kc = 0; kc < 8; ++kc) {
          if (kc < kclo || kc >= kchi) continue;
          const float p = __expf(s[m][kc][r] - mnew);
          s[m][kc][r] = p;
          rs += p;
        }
#pragma unroll
        for (int off = 1; off < 16; off <<= 1) rs += __shfl_xor(rs, off, 64);
        srun[m][r] = srun[m][r] * scale + rs;
        mrun[m][r] = mnew;
#pragma unroll
        for (int n = 0; n < 4; ++n) o[m][n][r] *= scale;
      }
    }

    // ---- P -> per-wave LDS (within-wave ordering, no barrier) ----
#pragma unroll
    for (int m = 0; m < 2; ++m)
#pragma unroll
      for (int kc = 0; kc < 8; ++kc) {
        if (kc < kclo || kc >= kchi) continue;
#pragma unroll
        for (int r = 0; r < 4; ++r)
          Pw[(m * 16 + lg * 4 + r) * 136 + kc * 16 + lr] = (__bf16)s[m][kc][r];
      }

    // ---- O += P V (direct V^T frags from global) ----
    const int kslo = kclo >> 1, kshi = kchi >> 1;
    const __bf16* vbase =
        vT + (size_t)(h * 64 + lr) * T_DIM + kb * 128 + lg * 8;
#pragma unroll
    for (int ks = 0; ks < 4; ++ks) {
      if (ks < kslo || ks >= kshi) continue;
      bf16x8 pa[2];
#pragma unroll
      for (int m = 0; m < 2; ++m)
        pa[m] = *(const bf16x8*)&Pw[(m * 16 + lr) * 136 + ks * 32 + lg * 8];
#pragma unroll
      for (int n = 0; n < 4; ++n) {
        const bf16x8 vb = *(const bf16x8*)(vbase + (size_t)n * 16 * T_DIM + ks * 32);
        o[0][n] = MFMA16(pa[0], vb, o[0][n]);
        o[1][n] = MFMA16(pa[1], vb, o[1][n]);
      }
    }
  }

  // ---- finalize: O / rowsum -> per-wave LDS -> coalesced 16B stores ----
#pragma unroll
  for (int m = 0; m < 2; ++m)
#pragma unroll
    for (int n = 0; n < 4; ++n)
#pragma unroll
      for (int r = 0; r < 4; ++r)
        Pw[(m * 16 + lg * 4 + r) * 136 + n * 16 + lr] =
            (__bf16)(o[m][n][r] / srun[m][r]);
#pragma unroll
  for (int i = 0; i < 4; ++i) {
    const int ci = i * 64 + l;
    const int qrow = ci >> 3;        // 0..31
    const int c8 = (ci & 7) * 8;     // 0..56
    const bf16x8 vv = *(const bf16x8*)&Pw[qrow * 136 + c8];
    *(bf16x8*)(out + (size_t)(blk * 128 + w * 32 + qrow) * D_DIM + h * 64 + c8) = vv;
  }
}

// ---------------------------------------------------------------------------
extern "C" void kernel_launch(void* const* d_in, const int* in_sizes, int n_in,
                              void* d_out, int out_size, void* d_ws, size_t ws_size,
                              hipStream_t stream) {
  (void)in_sizes; (void)n_in; (void)out_size; (void)ws_size;
  const float* x      = (const float*)d_in[0];
  const float* wq     = (const float*)d_in[1];
  const float* wk     = (const float*)d_in[2];
  const float* wv     = (const float*)d_in[3];
  const float* wo     = (const float*)d_in[4];
  const float* wg     = (const float*)d_in[5];
  const float* wd     = (const float*)d_in[6];
  const float* norm_g = (const float*)d_in[7];
  const float* norm_b = (const float*)d_in[8];
  const float* ffn_g  = (const float*)d_in[9];
  const float* ffn_b  = (const float*)d_in[10];
  float* out = (float*)d_out;

  // Workspace layout (112 MB total)
  char* ws = (char*)d_ws;
  constexpr size_t MB = 1ull << 20;
  __bf16* wqT  = (__bf16*)(ws + 0 * MB);    // [1024][1024]
  __bf16* wkT  = (__bf16*)(ws + 2 * MB);
  __bf16* wvT  = (__bf16*)(ws + 4 * MB);
  __bf16* woT  = (__bf16*)(ws + 6 * MB);
  __bf16* wgT  = (__bf16*)(ws + 8 * MB);    // [2048][1024]
  __bf16* wdT  = (__bf16*)(ws + 12 * MB);   // [1024][2048]
  __bf16* hbuf = (__bf16*)(ws + 16 * MB);   // h / attn_out / h2 (16 MB, reused)
  __bf16* qbf  = (__bf16*)(ws + 32 * MB);   // [T][D]
  __bf16* kbf  = (__bf16*)(ws + 48 * MB);   // [T][D]
  __bf16* vTbf = (__bf16*)(ws + 64 * MB);   // [D][T]
  float*  x2   = (float*)(ws + 80 * MB);    // [T][D] f32 (32 MB)
  __bf16* gbf  = (__bf16*)(ws + 32 * MB);   // [T][2D], reuses q+k (dead by then)

  // 1. weight transpose+convert
  transpose_cvt<<<dim3(32, 32), 256, 0, stream>>>(wq, wqT, 1024, 1024);
  transpose_cvt<<<dim3(32, 32), 256, 0, stream>>>(wk, wkT, 1024, 1024);
  transpose_cvt<<<dim3(32, 32), 256, 0, stream>>>(wv, wvT, 1024, 1024);
  transpose_cvt<<<dim3(32, 32), 256, 0, stream>>>(wo, woT, 1024, 1024);
  transpose_cvt<<<dim3(64, 32), 256, 0, stream>>>(wg, wgT, 1024, 2048);
  transpose_cvt<<<dim3(32, 64), 256, 0, stream>>>(wd, wdT, 2048, 1024);

  // 2. LN1
  ln_kernel<<<8192, 256, 0, stream>>>(x, norm_g, norm_b, hbuf);

  // 3. QKV projections (v written transposed for attention B-frags)
  gemm_bt<0><<<dim3(8, 64), 256, 0, stream>>>(hbuf, wqT, nullptr, qbf, 8192, 1024, 1024);
  gemm_bt<0><<<dim3(8, 64), 256, 0, stream>>>(hbuf, wkT, nullptr, kbf, 8192, 1024, 1024);
  gemm_bt<1><<<dim3(8, 64), 256, 0, stream>>>(hbuf, wvT, nullptr, vTbf, 8192, 1024, 1024);

  // 4. local attention -> hbuf (h dead)
  attn_kernel<<<1024, 256, 0, stream>>>(qbf, kbf, vTbf, hbuf);

  // 5. out-proj + residual: x2 = x + attn @ wo
  gemm_bt<2><<<dim3(8, 64), 256, 0, stream>>>(hbuf, woT, x, x2, 8192, 1024, 1024);

  // 6. LN2 -> hbuf (attn dead)
  ln_kernel<<<8192, 256, 0, stream>>>(x2, ffn_g, ffn_b, hbuf);

  // 7. gate: g = silu(h2 @ wg)
  gemm_bt<3><<<dim3(16, 64), 256, 0, stream>>>(hbuf, wgT, nullptr, gbf, 8192, 2048, 1024);

  // 8. down + residual: out = x2 + g @ wd
  gemm_bt<2><<<dim3(8, 64), 256, 0, stream>>>(gbf, wdT, x2, out, 8192, 1024, 2048);
}